// Round 7
// baseline (15147.127 us; speedup 1.0000x reference)
//
#include <hip/hip_runtime.h>
#include <math.h>

// Problem constants (fixed by reference: x (9,256,32,32) fp32, att (9,32,32) fp32)
#define MR 1024      // m = 32*32 query locations
#define NC 8192      // n = 8*32*32 target locations
#define NCH 256      // channels
#define OT_ITERS 1000
#define IMG_STRIDE 262144  // 256*1024 floats per image
#define PBLK 256           // persistent grid: 1 block/CU, 512 threads
#define L2EF 1.44269504088896340736f
#define LN2F 0.69314718055994530942f

__device__ inline float wredMax(float v){
#pragma unroll
  for (int m = 32; m >= 1; m >>= 1) v = fmaxf(v, __shfl_xor(v, m, 64));
  return v;
}
__device__ inline float wredMin(float v){
#pragma unroll
  for (int m = 32; m >= 1; m >>= 1) v = fminf(v, __shfl_xor(v, m, 64));
  return v;
}
__device__ inline float wredSum(float v){
#pragma unroll
  for (int m = 32; m >= 1; m >>= 1) v += __shfl_xor(v, m, 64);
  return v;
}

// monotone float<->uint key (for atomicMin/Max over floats incl. negatives)
__device__ inline unsigned fkey(float f){
  unsigned b = __float_as_uint(f);
  return (b & 0x80000000u) ? ~b : (b | 0x80000000u);
}
__device__ inline float funkey(unsigned k){
  return (k & 0x80000000u) ? __uint_as_float(k & 0x7fffffffu) : __uint_as_float(~k);
}

// coherent (agent/system-scope) vector loads: bypass stale L1/L2, read coherence point
__device__ inline float4 cload_f4(const float4* p){
  float4 r;
  asm volatile("global_load_dwordx4 %0, %1, off sc0 sc1\n\ts_waitcnt vmcnt(0)"
               : "=v"(r) : "v"(p) : "memory");
  return r;
}
__device__ inline void cload_f4x4(float4* r, const float4* p0, const float4* p1,
                                  const float4* p2, const float4* p3){
  asm volatile(
    "global_load_dwordx4 %0, %4, off sc0 sc1\n\t"
    "global_load_dwordx4 %1, %5, off sc0 sc1\n\t"
    "global_load_dwordx4 %2, %6, off sc0 sc1\n\t"
    "global_load_dwordx4 %3, %7, off sc0 sc1\n\t"
    "s_waitcnt vmcnt(0)"
    : "=&v"(r[0]), "=&v"(r[1]), "=&v"(r[2]), "=v"(r[3])
    : "v"(p0), "v"(p1), "v"(p2), "v"(p3)
    : "memory");
}
__device__ inline void astore(float* p, float val){
  __hip_atomic_store(p, val, __ATOMIC_RELAXED, __HIP_MEMORY_SCOPE_AGENT);
}

// K1: squared norms, log marginals, zero-init u,v,acc, minmax keys, barrier state
__global__ __launch_bounds__(256) void kPrep(const float* __restrict__ x,
                                             const float* __restrict__ att,
                                             float* __restrict__ qq, float* __restrict__ tt,
                                             float* __restrict__ logmu, float* __restrict__ lognu,
                                             float* __restrict__ u, float* __restrict__ v,
                                             float* __restrict__ acc, unsigned* __restrict__ prmI,
                                             int* __restrict__ bar){
  int idx = blockIdx.x * 256 + threadIdx.x;
  if (idx < 9216){
    int img = idx >> 10, pos = idx & 1023;
    const float* p = x + img * IMG_STRIDE + pos;
    float s = 0.f;
#pragma unroll 8
    for (int c = 0; c < NCH; ++c){ float a = p[c * 1024]; s += a * a; }
    float lg = logf(att[idx]);
    if (img == 0){ qq[idx] = s;        logmu[idx] = lg; }
    else         { tt[idx - 1024] = s; lognu[idx - 1024] = lg; }
  }
  if (idx < MR) u[idx] = 0.f;
  if (idx < NC) v[idx] = 0.f;
  if (idx < 1024) bar[idx] = 0;
  if (idx == 0){ *acc = 0.f; prmI[0] = 0xFFFFFFFFu; prmI[1] = 0u; }
}

// K2: M[i][j] = qq[i] + tt[j] - 2 * Q_i . T_j ; also global min/max via key atomics
__global__ __launch_bounds__(256) void kGemmM(const float* __restrict__ x,
                                              const float* __restrict__ qq,
                                              const float* __restrict__ tt,
                                              float* __restrict__ M,
                                              unsigned* __restrict__ prmI){
  __shared__ float As[16][68];
  __shared__ float Bs[16][68];
  __shared__ float smn[4], smx[4];
  int jb = blockIdx.x;
  int ib = blockIdx.y;
  int i0 = ib * 64;
  int j0 = jb * 64;
  int k  = j0 >> 10, p0 = j0 & 1023;
  const float* A = x + i0;
  const float* B = x + (1 + k) * IMG_STRIDE + p0;
  int tid = threadIdx.x;
  int lr = tid >> 4, lc = (tid & 15) * 4;
  int ty = tid >> 4, tx = tid & 15;
  float accv[4][4] = {};
  for (int kt = 0; kt < 16; ++kt){
    int c = kt * 16 + lr;
    float4 av = *(const float4*)(A + c * 1024 + lc);
    float4 bv = *(const float4*)(B + c * 1024 + lc);
    *(float4*)(&As[lr][lc]) = av;
    *(float4*)(&Bs[lr][lc]) = bv;
    __syncthreads();
#pragma unroll
    for (int kk = 0; kk < 16; ++kk){
      float4 a = *(const float4*)(&As[kk][ty * 4]);
      float4 b = *(const float4*)(&Bs[kk][tx * 4]);
      float ar[4] = {a.x, a.y, a.z, a.w};
      float br[4] = {b.x, b.y, b.z, b.w};
#pragma unroll
      for (int r = 0; r < 4; ++r)
#pragma unroll
        for (int cc = 0; cc < 4; ++cc) accv[r][cc] += ar[r] * br[cc];
    }
    __syncthreads();
  }
  float tmn = INFINITY, tmx = -INFINITY;
#pragma unroll
  for (int r = 0; r < 4; ++r){
    int i = i0 + ty * 4 + r;
    float qi = qq[i];
    float o[4];
#pragma unroll
    for (int cc = 0; cc < 4; ++cc){
      o[cc] = qi + tt[j0 + tx * 4 + cc] - 2.f * accv[r][cc];
      tmn = fminf(tmn, o[cc]); tmx = fmaxf(tmx, o[cc]);
    }
    float4 ov = { o[0], o[1], o[2], o[3] };
    *(float4*)(M + (long)i * NC + j0 + tx * 4) = ov;
  }
  int lane = tid & 63, w = tid >> 6;
  tmn = wredMin(tmn); tmx = wredMax(tmx);
  if (lane == 0){ smn[w] = tmn; smx[w] = tmx; }
  __syncthreads();
  if (tid == 0){
    float bmn = fminf(fminf(smn[0], smn[1]), fminf(smn[2], smn[3]));
    float bmx = fmaxf(fmaxf(smx[0], smx[1]), fmaxf(smx[2], smx[3]));
    atomicMin(&prmI[0], fkey(bmn));
    atomicMax(&prmI[1], fkey(bmx));
  }
}

// K2b: one pass over M -> Mq (u16 row-major) + Mtq (u16 transposed); writes prm scale
__global__ __launch_bounds__(256) void kQuantTrans(const float* __restrict__ M,
                                                   unsigned short* __restrict__ Mq,
                                                   unsigned short* __restrict__ Mtq,
                                                   float* __restrict__ prm){
  __shared__ float tile[64][65];
  const unsigned* prmI = (const unsigned*)prm;
  float mn = funkey(prmI[0]);
  float mx = funkey(prmI[1]);
  float rng = mx - mn;
  float inv = (rng > 0.f) ? 65535.0f / rng : 0.f;
  float sc  = (rng > 0.f) ? rng / 65535.0f : 0.f;
  int i0 = blockIdx.y * 64;
  int j0 = blockIdx.x * 64;
  int t = threadIdx.x;
  int tc = t & 63, tr = t >> 6;
#pragma unroll
  for (int rr = 0; rr < 64; rr += 4)
    tile[rr + tr][tc] = M[(long)(i0 + rr + tr) * NC + j0 + tc];
  __syncthreads();
#pragma unroll
  for (int rr = 0; rr < 64; rr += 4){
    float a = tile[rr + tr][tc];
    int qa = (int)lrintf((a - mn) * inv);
    qa = qa < 0 ? 0 : (qa > 65535 ? 65535 : qa);
    Mq[(long)(i0 + rr + tr) * NC + j0 + tc] = (unsigned short)qa;
    float b = tile[tc][rr + tr];
    int qb = (int)lrintf((b - mn) * inv);
    qb = qb < 0 ? 0 : (qb > 65535 ? 65535 : qb);
    Mtq[(long)(j0 + rr + tr) * MR + i0 + tc] = (unsigned short)qb;
  }
  if (blockIdx.x == 0 && blockIdx.y == 0 && t == 0){ prm[2] = mn; prm[3] = sc; }
}

// hierarchical epoch grid barrier: 8 groups x 32 blocks; relaxed atomics only
__device__ inline void gbar(int* bar, int g, int ep){
  __syncthreads();
  if (threadIdx.x == 0){
    asm volatile("s_waitcnt vmcnt(0)" ::: "memory");  // prior agent-stores complete
    int a = __hip_atomic_fetch_add(&bar[g * 32], 1, __ATOMIC_RELAXED, __HIP_MEMORY_SCOPE_AGENT);
    if (a == 32 * ep - 1){
      int go = __hip_atomic_fetch_add(&bar[512], 1, __ATOMIC_RELAXED, __HIP_MEMORY_SCOPE_AGENT);
      if (go == 8 * ep - 1){
#pragma unroll
        for (int g2 = 0; g2 < 8; ++g2)
          __hip_atomic_store(&bar[256 + g2 * 32], ep, __ATOMIC_RELAXED, __HIP_MEMORY_SCOPE_AGENT);
      }
    }
    while (__hip_atomic_load(&bar[256 + g * 32], __ATOMIC_RELAXED, __HIP_MEMORY_SCOPE_AGENT) < ep)
      __builtin_amdgcn_s_sleep(1);
  }
  __syncthreads();
}

// block reductions over 8 waves (512 threads)
__device__ inline float bredSum8(float* red, float x, int lane, int w){
  x = wredSum(x);
  __syncthreads();
  if (lane == 0) red[w] = x;
  __syncthreads();
  return ((red[0] + red[1]) + (red[2] + red[3])) + ((red[4] + red[5]) + (red[6] + red[7]));
}
__device__ inline float bredMax8(float* red, float x, int lane, int w){
  x = wredMax(x);
  __syncthreads();
  if (lane == 0) red[w] = x;
  __syncthreads();
  return fmaxf(fmaxf(fmaxf(red[0], red[1]), fmaxf(red[2], red[3])),
               fmaxf(fmaxf(red[4], red[5]), fmaxf(red[6], red[7])));
}

// persistent Sinkhorn: 256 blocks x 512 thr; block owns 4 u-rows + 32 v-cols.
// Single-pass LSE in log2 domain with carried per-row/col max estimate B
// (exact two-pass fallback when it<2 or the guarded sum over/underflows).
__global__ __launch_bounds__(512) void kSink3(const unsigned short* __restrict__ Mq,
                                              const unsigned short* __restrict__ Mtq,
                                              const float* __restrict__ logmu,
                                              const float* __restrict__ lognu,
                                              float* __restrict__ u,
                                              float* __restrict__ v,
                                              const float* __restrict__ prm,
                                              int* __restrict__ bar){
  __shared__ float shu[1024];
  __shared__ float red[8];
  int tid = threadIdx.x, b = blockIdx.x;
  int lane = tid & 63, w = tid >> 6;
  int g = b & 7;
  float mn = prm[2], s = prm[3];
  float s2 = s * L2EF;
  int r0 = 4 * b;
  float lmu[4];
#pragma unroll
  for (int r = 0; r < 4; ++r) lmu[r] = logmu[r0 + r];
  int jb = 32 * b + 4 * w;
  float lnu[4];
#pragma unroll
  for (int c = 0; c < 4; ++c) lnu[c] = lognu[jb + c];
  float B2u[4] = {0.f, 0.f, 0.f, 0.f};
  float B2v[4] = {0.f, 0.f, 0.f, 0.f};
  int ep = 0;

  for (int it = 0; it < OT_ITERS; ++it){
    // ---- load v (coherent, vectorized) -> registers, scaled to log2 domain ----
    const float4* vp = (const float4*)v;
    float4 vb[4];
    cload_f4x4(vb, vp + 2 * tid, vp + 2 * tid + 1, vp + 1024 + 2 * tid, vp + 1024 + 2 * tid + 1);
#pragma unroll
    for (int k = 0; k < 4; ++k){
      vb[k].x *= L2EF; vb[k].y *= L2EF; vb[k].z *= L2EF; vb[k].w *= L2EF;
    }
    // ---- u-pass: 4 rows sequentially; thread owns elements 8t..8t+7 & 4096+8t..+7 ----
#pragma unroll
    for (int r = 0; r < 4; ++r){
      const unsigned short* Rr = Mq + (long)(r0 + r) * NC;
      float Lv = 0.f;
      bool redo = true;
      if (it >= 2){
        float b2 = B2u[r];
        float part = 0.f;
#pragma unroll
        for (int h = 0; h < 2; ++h){
          uint4 q = *(const uint4*)(Rr + 4096 * h + 8 * tid);
          float4 v0 = vb[2 * h], v1 = vb[2 * h + 1];
          part += __builtin_exp2f(fmaf(s2, (float)(q.x & 0xFFFFu), v0.x) - b2);
          part += __builtin_exp2f(fmaf(s2, (float)(q.x >> 16),     v0.y) - b2);
          part += __builtin_exp2f(fmaf(s2, (float)(q.y & 0xFFFFu), v0.z) - b2);
          part += __builtin_exp2f(fmaf(s2, (float)(q.y >> 16),     v0.w) - b2);
          part += __builtin_exp2f(fmaf(s2, (float)(q.z & 0xFFFFu), v1.x) - b2);
          part += __builtin_exp2f(fmaf(s2, (float)(q.z >> 16),     v1.y) - b2);
          part += __builtin_exp2f(fmaf(s2, (float)(q.w & 0xFFFFu), v1.z) - b2);
          part += __builtin_exp2f(fmaf(s2, (float)(q.w >> 16),     v1.w) - b2);
        }
        float tot = bredSum8(red, part, lane, w);
        redo = !(tot > 0.f && tot < 3.0e38f);
        Lv = b2 + __builtin_log2f(tot);
      }
      if (redo){
        float tv[16];
        float mx = -INFINITY;
#pragma unroll
        for (int h = 0; h < 2; ++h){
          uint4 q = *(const uint4*)(Rr + 4096 * h + 8 * tid);
          float4 v0 = vb[2 * h], v1 = vb[2 * h + 1];
          tv[h*8+0] = fmaf(s2, (float)(q.x & 0xFFFFu), v0.x);
          tv[h*8+1] = fmaf(s2, (float)(q.x >> 16),     v0.y);
          tv[h*8+2] = fmaf(s2, (float)(q.y & 0xFFFFu), v0.z);
          tv[h*8+3] = fmaf(s2, (float)(q.y >> 16),     v0.w);
          tv[h*8+4] = fmaf(s2, (float)(q.z & 0xFFFFu), v1.x);
          tv[h*8+5] = fmaf(s2, (float)(q.z >> 16),     v1.y);
          tv[h*8+6] = fmaf(s2, (float)(q.w & 0xFFFFu), v1.z);
          tv[h*8+7] = fmaf(s2, (float)(q.w >> 16),     v1.w);
#pragma unroll
          for (int e = 0; e < 8; ++e) mx = fmaxf(mx, tv[h*8+e]);
        }
        float bmx = bredMax8(red, mx, lane, w);
        float p2 = 0.f;
#pragma unroll
        for (int q2 = 0; q2 < 16; ++q2) p2 += __builtin_exp2f(tv[q2] - bmx);
        float tot2 = bredSum8(red, p2, lane, w);
        Lv = bmx + __builtin_log2f(tot2);
      }
      B2u[r] = Lv;
      if (tid == 0) astore(u + r0 + r, lmu[r] - mn - Lv * LN2F);
    }
    gbar(bar, g, ++ep);   // u complete everywhere

    // ---- stage u (coherent) into LDS, scaled ----
    if (tid < 256){
      float4 uu = cload_f4((const float4*)u + tid);
      uu.x *= L2EF; uu.y *= L2EF; uu.z *= L2EF; uu.w *= L2EF;
      *(float4*)(&shu[tid * 4]) = uu;
    }
    __syncthreads();
    float4 uf[4];
#pragma unroll
    for (int k = 0; k < 4; ++k) uf[k] = *(const float4*)(&shu[4 * (k * 64 + lane)]);
    // ---- v-pass: 4 cols per wave; lane owns elements 4l.., 256+4l.., 512+.., 768+.. ----
#pragma unroll
    for (int c = 0; c < 4; ++c){
      int j = jb + c;
      const unsigned short* Rc = Mtq + (long)j * MR;
      float Lv = 0.f;
      bool redo = true;
      if (it >= 2){
        float b2 = B2v[c];
        float part = 0.f;
#pragma unroll
        for (int k = 0; k < 4; ++k){
          uint2 q = *(const uint2*)(Rc + 4 * (k * 64 + lane));
          part += __builtin_exp2f(fmaf(s2, (float)(q.x & 0xFFFFu), uf[k].x) - b2);
          part += __builtin_exp2f(fmaf(s2, (float)(q.x >> 16),     uf[k].y) - b2);
          part += __builtin_exp2f(fmaf(s2, (float)(q.y & 0xFFFFu), uf[k].z) - b2);
          part += __builtin_exp2f(fmaf(s2, (float)(q.y >> 16),     uf[k].w) - b2);
        }
        float tot = wredSum(part);
        redo = !(tot > 0.f && tot < 3.0e38f);
        Lv = b2 + __builtin_log2f(tot);
      }
      if (redo){
        float tvv[16];
        float mx = -INFINITY;
#pragma unroll
        for (int k = 0; k < 4; ++k){
          uint2 q = *(const uint2*)(Rc + 4 * (k * 64 + lane));
          tvv[k*4+0] = fmaf(s2, (float)(q.x & 0xFFFFu), uf[k].x);
          tvv[k*4+1] = fmaf(s2, (float)(q.x >> 16),     uf[k].y);
          tvv[k*4+2] = fmaf(s2, (float)(q.y & 0xFFFFu), uf[k].z);
          tvv[k*4+3] = fmaf(s2, (float)(q.y >> 16),     uf[k].w);
          mx = fmaxf(mx, fmaxf(fmaxf(tvv[k*4], tvv[k*4+1]), fmaxf(tvv[k*4+2], tvv[k*4+3])));
        }
        mx = wredMax(mx);
        float p2 = 0.f;
#pragma unroll
        for (int q2 = 0; q2 < 16; ++q2) p2 += __builtin_exp2f(tvv[q2] - mx);
        p2 = wredSum(p2);
        Lv = mx + __builtin_log2f(p2);
      }
      B2v[c] = Lv;
      if (lane == 0) astore(v + j, lnu[c] - mn - Lv * LN2F);
    }
    gbar(bar, g, ++ep);   // v complete everywhere
  }
}

// fallback (R4 path): used only if cooperative launch fails
__global__ __launch_bounds__(256) void kUPassQ(const unsigned short* __restrict__ Mq,
                                               const float* __restrict__ v,
                                               const float* __restrict__ logmu,
                                               float* __restrict__ u,
                                               const float* __restrict__ prm){
  int b = blockIdx.x, tid = threadIdx.x;
  float mn = prm[2], s = prm[3];
  int r0 = 2 * b;
  const unsigned short* R0 = Mq + (long)r0 * NC;
  const unsigned short* R1 = R0 + NC;
  float t0[32], t1[32];
  float mx0 = -INFINITY, mx1 = -INFINITY;
#pragma unroll
  for (int kb = 0; kb < 4; ++kb){
    int cidx = kb * 2048 + tid * 8;
    uint4 qa = *(const uint4*)(R0 + cidx);
    uint4 qb = *(const uint4*)(R1 + cidx);
    float4 v0 = *(const float4*)(v + cidx);
    float4 v1 = *(const float4*)(v + cidx + 4);
    float a0 = fmaf(s, (float)(qa.x & 0xFFFFu), v0.x);
    float a1 = fmaf(s, (float)(qa.x >> 16),     v0.y);
    float a2 = fmaf(s, (float)(qa.y & 0xFFFFu), v0.z);
    float a3 = fmaf(s, (float)(qa.y >> 16),     v0.w);
    float a4 = fmaf(s, (float)(qa.z & 0xFFFFu), v1.x);
    float a5 = fmaf(s, (float)(qa.z >> 16),     v1.y);
    float a6 = fmaf(s, (float)(qa.w & 0xFFFFu), v1.z);
    float a7 = fmaf(s, (float)(qa.w >> 16),     v1.w);
    float c0 = fmaf(s, (float)(qb.x & 0xFFFFu), v0.x);
    float c1 = fmaf(s, (float)(qb.x >> 16),     v0.y);
    float c2 = fmaf(s, (float)(qb.y & 0xFFFFu), v0.z);
    float c3 = fmaf(s, (float)(qb.y >> 16),     v0.w);
    float c4 = fmaf(s, (float)(qb.z & 0xFFFFu), v1.x);
    float c5 = fmaf(s, (float)(qb.z >> 16),     v1.y);
    float c6 = fmaf(s, (float)(qb.w & 0xFFFFu), v1.z);
    float c7 = fmaf(s, (float)(qb.w >> 16),     v1.w);
    t0[kb*8+0]=a0; t0[kb*8+1]=a1; t0[kb*8+2]=a2; t0[kb*8+3]=a3;
    t0[kb*8+4]=a4; t0[kb*8+5]=a5; t0[kb*8+6]=a6; t0[kb*8+7]=a7;
    t1[kb*8+0]=c0; t1[kb*8+1]=c1; t1[kb*8+2]=c2; t1[kb*8+3]=c3;
    t1[kb*8+4]=c4; t1[kb*8+5]=c5; t1[kb*8+6]=c6; t1[kb*8+7]=c7;
    mx0 = fmaxf(mx0, fmaxf(fmaxf(fmaxf(a0,a1),fmaxf(a2,a3)), fmaxf(fmaxf(a4,a5),fmaxf(a6,a7))));
    mx1 = fmaxf(mx1, fmaxf(fmaxf(fmaxf(c0,c1),fmaxf(c2,c3)), fmaxf(fmaxf(c4,c5),fmaxf(c6,c7))));
  }
  __shared__ float redA0[4], redA1[4], redB0[4], redB1[4];
  int lane = tid & 63, w = tid >> 6;
  float wm0 = wredMax(mx0), wm1 = wredMax(mx1);
  if (lane == 0){ redA0[w] = wm0; redA1[w] = wm1; }
  __syncthreads();
  float bm0 = fmaxf(fmaxf(redA0[0], redA0[1]), fmaxf(redA0[2], redA0[3]));
  float bm1 = fmaxf(fmaxf(redA1[0], redA1[1]), fmaxf(redA1[2], redA1[3]));
  float s0 = 0.f, s1 = 0.f;
#pragma unroll
  for (int q = 0; q < 32; ++q){ s0 += __expf(t0[q] - bm0); s1 += __expf(t1[q] - bm1); }
  s0 = wredSum(s0); s1 = wredSum(s1);
  if (lane == 0){ redB0[w] = s0; redB1[w] = s1; }
  __syncthreads();
  if (tid == 0){
    u[r0]     = logmu[r0]     - mn - (bm0 + __logf(redB0[0] + redB0[1] + redB0[2] + redB0[3]));
    u[r0 + 1] = logmu[r0 + 1] - mn - (bm1 + __logf(redB1[0] + redB1[1] + redB1[2] + redB1[3]));
  }
}

__global__ __launch_bounds__(256) void kVPassQ(const unsigned short* __restrict__ Mtq,
                                               const float* __restrict__ u,
                                               const float* __restrict__ lognu,
                                               float* __restrict__ v,
                                               const float* __restrict__ prm){
  __shared__ float ulds[1024];
  int tid = threadIdx.x;
  float mn = prm[2], s = prm[3];
  *(float4*)(&ulds[tid * 4]) = *(const float4*)(u + tid * 4);
  __syncthreads();
  int w = tid >> 6, lane = tid & 63;
#pragma unroll
  for (int cc = 0; cc < 4; ++cc){
    int j = blockIdx.x * 16 + w * 4 + cc;
    const unsigned short* R = Mtq + (long)j * MR;
    uint4 qa = *(const uint4*)(R + lane * 8);
    uint4 qb = *(const uint4*)(R + 512 + lane * 8);
    float4 ua0 = *(const float4*)(&ulds[lane * 8]);
    float4 ua1 = *(const float4*)(&ulds[lane * 8 + 4]);
    float4 ub0 = *(const float4*)(&ulds[512 + lane * 8]);
    float4 ub1 = *(const float4*)(&ulds[512 + lane * 8 + 4]);
    float tv[16];
    tv[0]  = fmaf(s, (float)(qa.x & 0xFFFFu), ua0.x);
    tv[1]  = fmaf(s, (float)(qa.x >> 16),     ua0.y);
    tv[2]  = fmaf(s, (float)(qa.y & 0xFFFFu), ua0.z);
    tv[3]  = fmaf(s, (float)(qa.y >> 16),     ua0.w);
    tv[4]  = fmaf(s, (float)(qa.z & 0xFFFFu), ua1.x);
    tv[5]  = fmaf(s, (float)(qa.z >> 16),     ua1.y);
    tv[6]  = fmaf(s, (float)(qa.w & 0xFFFFu), ua1.z);
    tv[7]  = fmaf(s, (float)(qa.w >> 16),     ua1.w);
    tv[8]  = fmaf(s, (float)(qb.x & 0xFFFFu), ub0.x);
    tv[9]  = fmaf(s, (float)(qb.x >> 16),     ub0.y);
    tv[10] = fmaf(s, (float)(qb.y & 0xFFFFu), ub0.z);
    tv[11] = fmaf(s, (float)(qb.y >> 16),     ub0.w);
    tv[12] = fmaf(s, (float)(qb.z & 0xFFFFu), ub1.x);
    tv[13] = fmaf(s, (float)(qb.z >> 16),     ub1.y);
    tv[14] = fmaf(s, (float)(qb.w & 0xFFFFu), ub1.z);
    tv[15] = fmaf(s, (float)(qb.w >> 16),     ub1.w);
    float mx = -INFINITY;
#pragma unroll
    for (int q = 0; q < 16; ++q) mx = fmaxf(mx, tv[q]);
    mx = wredMax(mx);
    float sm = 0.f;
#pragma unroll
    for (int q = 0; q < 16; ++q) sm += __expf(tv[q] - mx);
    sm = wredSum(sm);
    if (lane == 0) v[j] = lognu[j] - mn - (mx + __logf(sm));
  }
}

// K5: o = P@T rows, diff = mu*Q - o, acc += sum_i ||diff_i||_2 ; 4 rows per block
__global__ __launch_bounds__(256) void kFinal(const float* __restrict__ x,
                                              const float* __restrict__ att,
                                              const float* __restrict__ M,
                                              const float* __restrict__ u,
                                              const float* __restrict__ v,
                                              float* __restrict__ acc){
  __shared__ float pch[4][256];
  __shared__ float redS[4];
  int tid = threadIdx.x;
  int r0 = blockIdx.x * 4;
  float u4[4];
#pragma unroll
  for (int rr = 0; rr < 4; ++rr) u4[rr] = u[r0 + rr];
  float o[4] = {0.f, 0.f, 0.f, 0.f};
  for (int jc = 0; jc < NC; jc += 256){
    float vv = v[jc + tid];
#pragma unroll
    for (int rr = 0; rr < 4; ++rr)
      pch[rr][tid] = __expf(M[(long)(r0 + rr) * NC + jc + tid] + u4[rr] + vv);
    __syncthreads();
    int k = jc >> 10;
    const float* Tp = x + (1 + k) * IMG_STRIDE + tid * 1024 + (jc & 1023);
    for (int jj = 0; jj < 256; jj += 4){
      float4 tv = *(const float4*)(Tp + jj);
      float tq[4] = {tv.x, tv.y, tv.z, tv.w};
#pragma unroll
      for (int q = 0; q < 4; ++q){
        o[0] += pch[0][jj + q] * tq[q];
        o[1] += pch[1][jj + q] * tq[q];
        o[2] += pch[2][jj + q] * tq[q];
        o[3] += pch[3][jj + q] * tq[q];
      }
    }
    __syncthreads();
  }
  int lane = tid & 63, wid = tid >> 6;
  float dtot = 0.f;
#pragma unroll
  for (int rr = 0; rr < 4; ++rr){
    float mu = att[r0 + rr];
    float qv = x[tid * 1024 + (r0 + rr)];
    float diff = mu * qv - o[rr];
    float wsum = wredSum(diff * diff);
    if (lane == 0) redS[wid] = wsum;
    __syncthreads();
    if (tid == 0) dtot += sqrtf(redS[0] + redS[1] + redS[2] + redS[3]);
    __syncthreads();
  }
  if (tid == 0) atomicAdd(acc, dtot);
}

// K6: apply label/margin, write scalar output
__global__ void kOut(const float* __restrict__ acc, const int* __restrict__ label,
                     float* __restrict__ out){
  if (threadIdx.x == 0 && blockIdx.x == 0){
    float d = *acc;
    out[0] = (*label) ? d : fmaxf(0.7f - d, 0.f);
  }
}

extern "C" void kernel_launch(void* const* d_in, const int* in_sizes, int n_in,
                              void* d_out, int out_size, void* d_ws, size_t ws_size,
                              hipStream_t stream){
  const float* x   = (const float*)d_in[0];
  const float* att = (const float*)d_in[1];
  const int* label = (const int*)d_in[2];
  float* W = (float*)d_ws;
  float* out = (float*)d_out;

  float* M = W;                                                   // 32 MB
  unsigned short* Mq  = (unsigned short*)(W + 8388608);           // 16 MB
  unsigned short* Mtq = (unsigned short*)(W + 8388608 + 4194304); // 16 MB
  float* S     = W + 16777216;
  float* qq    = S;
  float* tt    = qq + 1024;
  float* logmu = tt + 8192;
  float* lognu = logmu + 1024;
  float* u     = lognu + 8192;
  float* v     = u + 1024;
  float* acc   = v + 8192;
  float* prm   = acc + 1;           // [0]=min key, [1]=max key, [2]=mn, [3]=scale
  unsigned* prmI = (unsigned*)prm;
  int*   bar   = (int*)(prm + 4);   // 1024 ints barrier state

  hipLaunchKernelGGL(kPrep, dim3(37), dim3(256), 0, stream, x, att, qq, tt, logmu, lognu, u, v, acc, prmI, bar);
  hipLaunchKernelGGL(kGemmM, dim3(128, 16), dim3(256), 0, stream, x, qq, tt, M, prmI);
  hipLaunchKernelGGL(kQuantTrans, dim3(128, 16), dim3(256), 0, stream, M, Mq, Mtq, prm);

  void* args[] = { (void*)&Mq, (void*)&Mtq, (void*)&logmu, (void*)&lognu,
                   (void*)&u, (void*)&v, (void*)&prm, (void*)&bar };
  hipError_t rc = hipLaunchCooperativeKernel((const void*)kSink3,
                                             dim3(PBLK), dim3(512), args, 0, stream);
  if (rc != hipSuccess){
    for (int it = 0; it < OT_ITERS; ++it){
      hipLaunchKernelGGL(kUPassQ, dim3(512), dim3(256), 0, stream, Mq, v, logmu, u, prm);
      hipLaunchKernelGGL(kVPassQ, dim3(512), dim3(256), 0, stream, Mtq, u, lognu, v, prm);
    }
  }
  hipLaunchKernelGGL(kFinal, dim3(256), dim3(256), 0, stream, x, att, M, u, v, acc);
  hipLaunchKernelGGL(kOut, dim3(1), dim3(1), 0, stream, acc, label, out);
}

// Round 8
// 12912.094 us; speedup vs baseline: 1.1731x; 1.1731x over previous
//
#include <hip/hip_runtime.h>
#include <math.h>

// Problem constants (fixed by reference: x (9,256,32,32) fp32, att (9,32,32) fp32)
#define MR 1024      // m = 32*32 query locations
#define NC 8192      // n = 8*32*32 target locations
#define NCH 256      // channels
#define OT_ITERS 1000
#define IMG_STRIDE 262144  // 256*1024 floats per image
#define PBLK 256           // persistent grid: 1 block/CU, 512 threads
#define L2EF 1.44269504088896340736f
#define LN2F 0.69314718055994530942f
#define CAPR 768           // row shortlist capacity (per row)
#define CAPC 384           // col shortlist capacity (per col)
#define MARG2 40.0f        // shortlist margin, log2 units: excluded < 2^-40 each
#define WARMUP 16          // full-scan iterations before first list build

__device__ inline float wredMax(float v){
#pragma unroll
  for (int m = 32; m >= 1; m >>= 1) v = fmaxf(v, __shfl_xor(v, m, 64));
  return v;
}
__device__ inline float wredMin(float v){
#pragma unroll
  for (int m = 32; m >= 1; m >>= 1) v = fminf(v, __shfl_xor(v, m, 64));
  return v;
}
__device__ inline float wredSum(float v){
#pragma unroll
  for (int m = 32; m >= 1; m >>= 1) v += __shfl_xor(v, m, 64);
  return v;
}

__device__ inline unsigned fkey(float f){
  unsigned b = __float_as_uint(f);
  return (b & 0x80000000u) ? ~b : (b | 0x80000000u);
}
__device__ inline float funkey(unsigned k){
  return (k & 0x80000000u) ? __uint_as_float(k & 0x7fffffffu) : __uint_as_float(~k);
}

// agent-scope (device-coherent) scalar load/store for u/v exchange
__device__ inline float aload(const float* p){
  return __hip_atomic_load(p, __ATOMIC_RELAXED, __HIP_MEMORY_SCOPE_AGENT);
}
__device__ inline void astore(float* p, float val){
  __hip_atomic_store(p, val, __ATOMIC_RELAXED, __HIP_MEMORY_SCOPE_AGENT);
}

// K1: squared norms, log marginals, zero-init u,v,acc, minmax keys, barrier state
__global__ __launch_bounds__(256) void kPrep(const float* __restrict__ x,
                                             const float* __restrict__ att,
                                             float* __restrict__ qq, float* __restrict__ tt,
                                             float* __restrict__ logmu, float* __restrict__ lognu,
                                             float* __restrict__ u, float* __restrict__ v,
                                             float* __restrict__ acc, unsigned* __restrict__ prmI,
                                             int* __restrict__ bar){
  int idx = blockIdx.x * 256 + threadIdx.x;
  if (idx < 9216){
    int img = idx >> 10, pos = idx & 1023;
    const float* p = x + img * IMG_STRIDE + pos;
    float s = 0.f;
#pragma unroll 8
    for (int c = 0; c < NCH; ++c){ float a = p[c * 1024]; s += a * a; }
    float lg = logf(att[idx]);
    if (img == 0){ qq[idx] = s;        logmu[idx] = lg; }
    else         { tt[idx - 1024] = s; lognu[idx - 1024] = lg; }
  }
  if (idx < MR) u[idx] = 0.f;
  if (idx < NC) v[idx] = 0.f;
  if (idx < 1024) bar[idx] = 0;
  if (idx == 0){ *acc = 0.f; prmI[0] = 0xFFFFFFFFu; prmI[1] = 0u; }
}

// K2: M[i][j] = qq[i] + tt[j] - 2 * Q_i . T_j ; also global min/max via key atomics
__global__ __launch_bounds__(256) void kGemmM(const float* __restrict__ x,
                                              const float* __restrict__ qq,
                                              const float* __restrict__ tt,
                                              float* __restrict__ M,
                                              unsigned* __restrict__ prmI){
  __shared__ float As[16][68];
  __shared__ float Bs[16][68];
  __shared__ float smn[4], smx[4];
  int jb = blockIdx.x;
  int ib = blockIdx.y;
  int i0 = ib * 64;
  int j0 = jb * 64;
  int k  = j0 >> 10, p0 = j0 & 1023;
  const float* A = x + i0;
  const float* B = x + (1 + k) * IMG_STRIDE + p0;
  int tid = threadIdx.x;
  int lr = tid >> 4, lc = (tid & 15) * 4;
  int ty = tid >> 4, tx = tid & 15;
  float accv[4][4] = {};
  for (int kt = 0; kt < 16; ++kt){
    int c = kt * 16 + lr;
    float4 av = *(const float4*)(A + c * 1024 + lc);
    float4 bv = *(const float4*)(B + c * 1024 + lc);
    *(float4*)(&As[lr][lc]) = av;
    *(float4*)(&Bs[lr][lc]) = bv;
    __syncthreads();
#pragma unroll
    for (int kk = 0; kk < 16; ++kk){
      float4 a = *(const float4*)(&As[kk][ty * 4]);
      float4 b = *(const float4*)(&Bs[kk][tx * 4]);
      float ar[4] = {a.x, a.y, a.z, a.w};
      float br[4] = {b.x, b.y, b.z, b.w};
#pragma unroll
      for (int r = 0; r < 4; ++r)
#pragma unroll
        for (int cc = 0; cc < 4; ++cc) accv[r][cc] += ar[r] * br[cc];
    }
    __syncthreads();
  }
  float tmn = INFINITY, tmx = -INFINITY;
#pragma unroll
  for (int r = 0; r < 4; ++r){
    int i = i0 + ty * 4 + r;
    float qi = qq[i];
    float o[4];
#pragma unroll
    for (int cc = 0; cc < 4; ++cc){
      o[cc] = qi + tt[j0 + tx * 4 + cc] - 2.f * accv[r][cc];
      tmn = fminf(tmn, o[cc]); tmx = fmaxf(tmx, o[cc]);
    }
    float4 ov = { o[0], o[1], o[2], o[3] };
    *(float4*)(M + (long)i * NC + j0 + tx * 4) = ov;
  }
  int lane = tid & 63, w = tid >> 6;
  tmn = wredMin(tmn); tmx = wredMax(tmx);
  if (lane == 0){ smn[w] = tmn; smx[w] = tmx; }
  __syncthreads();
  if (tid == 0){
    float bmn = fminf(fminf(smn[0], smn[1]), fminf(smn[2], smn[3]));
    float bmx = fmaxf(fmaxf(smx[0], smx[1]), fmaxf(smx[2], smx[3]));
    atomicMin(&prmI[0], fkey(bmn));
    atomicMax(&prmI[1], fkey(bmx));
  }
}

// K2b: one pass over M -> Mq (u16 row-major, fallback path) + Mtq (u16 transposed)
__global__ __launch_bounds__(256) void kQuantTrans(const float* __restrict__ M,
                                                   unsigned short* __restrict__ Mq,
                                                   unsigned short* __restrict__ Mtq,
                                                   float* __restrict__ prm){
  __shared__ float tile[64][65];
  const unsigned* prmI = (const unsigned*)prm;
  float mn = funkey(prmI[0]);
  float mx = funkey(prmI[1]);
  float rng = mx - mn;
  float inv = (rng > 0.f) ? 65535.0f / rng : 0.f;
  float sc  = (rng > 0.f) ? rng / 65535.0f : 0.f;
  int i0 = blockIdx.y * 64;
  int j0 = blockIdx.x * 64;
  int t = threadIdx.x;
  int tc = t & 63, tr = t >> 6;
#pragma unroll
  for (int rr = 0; rr < 64; rr += 4)
    tile[rr + tr][tc] = M[(long)(i0 + rr + tr) * NC + j0 + tc];
  __syncthreads();
#pragma unroll
  for (int rr = 0; rr < 64; rr += 4){
    float a = tile[rr + tr][tc];
    int qa = (int)lrintf((a - mn) * inv);
    qa = qa < 0 ? 0 : (qa > 65535 ? 65535 : qa);
    Mq[(long)(i0 + rr + tr) * NC + j0 + tc] = (unsigned short)qa;
    float b = tile[tc][rr + tr];
    int qb = (int)lrintf((b - mn) * inv);
    qb = qb < 0 ? 0 : (qb > 65535 ? 65535 : qb);
    Mtq[(long)(j0 + rr + tr) * MR + i0 + tc] = (unsigned short)qb;
  }
  if (blockIdx.x == 0 && blockIdx.y == 0 && t == 0){ prm[2] = mn; prm[3] = sc; }
}

// hierarchical epoch grid barrier: 8 groups x 32 blocks; relaxed agent atomics only
__device__ inline void gbar(int* bar, int g, int ep){
  __syncthreads();
  if (threadIdx.x == 0){
    asm volatile("s_waitcnt vmcnt(0)" ::: "memory");  // drain prior agent-stores
    int a = __hip_atomic_fetch_add(&bar[g * 32], 1, __ATOMIC_RELAXED, __HIP_MEMORY_SCOPE_AGENT);
    if (a == 32 * ep - 1){
      int go = __hip_atomic_fetch_add(&bar[512], 1, __ATOMIC_RELAXED, __HIP_MEMORY_SCOPE_AGENT);
      if (go == 8 * ep - 1){
#pragma unroll
        for (int g2 = 0; g2 < 8; ++g2)
          __hip_atomic_store(&bar[256 + g2 * 32], ep, __ATOMIC_RELAXED, __HIP_MEMORY_SCOPE_AGENT);
      }
    }
    while (__hip_atomic_load(&bar[256 + g * 32], __ATOMIC_RELAXED, __HIP_MEMORY_SCOPE_AGENT) < ep)
      __builtin_amdgcn_s_sleep(1);
  }
  __syncthreads();
}

// persistent sparse Sinkhorn: 256 blocks x 512 thr; block owns 4 u-rows + 32 v-cols.
// LDS-private shortlists of LSE support (margin 2^-40), rebuilt locally every 64
// iters from exact M / Mtq; exact full-scan fallback for warmup & overflow.
__global__ __launch_bounds__(512) void kSink4(const float* __restrict__ M,
                                              const unsigned short* __restrict__ Mtq,
                                              const float* __restrict__ logmu,
                                              const float* __restrict__ lognu,
                                              float* __restrict__ u,
                                              float* __restrict__ v,
                                              const float* __restrict__ prm,
                                              int* __restrict__ bar){
  __shared__ unsigned rowl[4 * CAPR];   // 12 KB
  __shared__ unsigned coll[32 * CAPC];  // 48 KB
  __shared__ float red[16];
  __shared__ int cnts[36];              // [0..3] rows, [4..35] cols
  int tid = threadIdx.x, b = blockIdx.x;
  int lane = tid & 63, w = tid >> 6;
  int g = b & 7;
  float mn = prm[2], s = prm[3];
  float s2 = s * L2EF;
  float inv = (s > 0.f) ? 1.0f / s : 0.f;
  int r0 = 4 * b;
  int jb0 = 32 * b;
  int r = w >> 1;                 // this wave's row (2 waves per row)
  int idx = (w & 1) * 64 + lane;  // 0..127 within the row pair
  int i_row = r0 + r;
  const float* Mr = M + (long)i_row * NC;
  float lmu_r = logmu[i_row];
  float lnu4[4];
#pragma unroll
  for (int cc = 0; cc < 4; ++cc) lnu4[cc] = lognu[jb0 + w * 4 + cc];

  if (tid < 36) cnts[tid] = -1;   // warmup: all full-scan
  __syncthreads();
  int ep = 0;

  for (int it = 0; it < OT_ITERS; ++it){
    bool rebuild = (it >= WARMUP) && (((it - WARMUP) & 63) == 0);

    // ---- row shortlist rebuild (block-local; uses current v) ----
    if (rebuild){
      if (tid < 36) cnts[tid] = 0;
      __syncthreads();
      float mxb = -INFINITY;
      for (int k = 0; k < 64; ++k){
        int j = idx + k * 128;
        float a = (Mr[j] - mn) + aload(v + j);
        mxb = fmaxf(mxb, a);
      }
      mxb = wredMax(mxb);
      if (lane == 0) red[w] = mxb;
      __syncthreads();
      float thr = fmaxf(red[2 * r], red[2 * r + 1]) - MARG2 * LN2F; // natural-log domain
      for (int k = 0; k < 64; ++k){
        int j = idx + k * 128;
        float mv = Mr[j] - mn;
        float a = mv + aload(v + j);
        if (a >= thr){
          int p = atomicAdd(&cnts[r], 1);
          if (p < CAPR){
            int qv = (int)lrintf(mv * inv);
            qv = qv < 0 ? 0 : (qv > 65535 ? 65535 : qv);
            rowl[r * CAPR + p] = ((unsigned)qv << 13) | (unsigned)j;
          }
        }
      }
      __syncthreads();
      if (tid < 4 && cnts[tid] > CAPR) cnts[tid] = -1;
      __syncthreads();
    }

    // ---- u-pass: row r (128 threads), shortlist or exact full scan ----
    {
      int cnt = cnts[r];
      float t2v[6];
      float mx = -INFINITY;
      if (cnt >= 0){
#pragma unroll
        for (int q = 0; q < 6; ++q){
          int e = idx + q * 128;
          bool act = (e < cnt);
          unsigned ent = rowl[r * CAPR + (act ? e : 0)];
          int j = act ? (int)(ent & 8191u) : 0;
          float vj = aload(v + j);
          float t2 = act ? fmaf(s2, (float)(ent >> 13), L2EF * vj) : -INFINITY;
          t2v[q] = t2;
          mx = fmaxf(mx, t2);
        }
      } else {
        for (int k = 0; k < 64; ++k){
          int j = idx + k * 128;
          float a = (Mr[j] - mn) + aload(v + j);
          mx = fmaxf(mx, a * L2EF);
        }
      }
      mx = wredMax(mx);
      if (lane == 0) red[w] = mx;
      __syncthreads();
      float bmx = fmaxf(red[2 * r], red[2 * r + 1]);
      float sm = 0.f;
      if (cnt >= 0){
#pragma unroll
        for (int q = 0; q < 6; ++q) sm += __builtin_exp2f(t2v[q] - bmx);
      } else {
        for (int k = 0; k < 64; ++k){
          int j = idx + k * 128;
          float a = (Mr[j] - mn) + aload(v + j);
          sm += __builtin_exp2f(a * L2EF - bmx);
        }
      }
      sm = wredSum(sm);
      if (lane == 0) red[8 + w] = sm;
      __syncthreads();
      if (idx == 0){
        float tot = red[8 + 2 * r] + red[8 + 2 * r + 1];
        float Lv = bmx + __builtin_log2f(tot);
        astore(u + i_row, lmu_r - mn - Lv * LN2F);
      }
    }
    gbar(bar, g, ++ep);   // u complete everywhere

    // ---- col shortlist rebuild (block-local; uses fresh u) ----
    if (rebuild){
#pragma unroll
      for (int cc = 0; cc < 4; ++cc){
        int cj = w * 4 + cc;
        const unsigned short* Rc = Mtq + (long)(jb0 + cj) * MR;
        float mx = -INFINITY;
        for (int k = 0; k < 16; ++k){
          int i = lane + k * 64;
          float t2 = fmaf(s2, (float)Rc[i], L2EF * aload(u + i));
          mx = fmaxf(mx, t2);
        }
        mx = wredMax(mx);
        float thr = mx - MARG2;
        for (int k = 0; k < 16; ++k){
          int i = lane + k * 64;
          float qv = (float)Rc[i];
          float t2 = fmaf(s2, qv, L2EF * aload(u + i));
          if (t2 >= thr){
            int p = atomicAdd(&cnts[4 + cj], 1);
            if (p < CAPC) coll[cj * CAPC + p] = ((unsigned)Rc[i] << 10) | (unsigned)i;
          }
        }
      }
      __syncthreads();
      if (tid >= 4 && tid < 36 && cnts[tid] > CAPC) cnts[tid] = -1;
      __syncthreads();
    }

    // ---- v-pass: 4 cols per wave, shortlist or exact full scan ----
#pragma unroll
    for (int cc = 0; cc < 4; ++cc){
      int cj = w * 4 + cc;
      int j = jb0 + cj;
      int cnt = cnts[4 + cj];
      float t2v[6];
      float mx = -INFINITY;
      if (cnt >= 0){
#pragma unroll
        for (int q = 0; q < 6; ++q){
          int e = lane + q * 64;
          bool act = (e < cnt);
          unsigned ent = coll[cj * CAPC + (act ? e : 0)];
          int i = act ? (int)(ent & 1023u) : 0;
          float ui = aload(u + i);
          float t2 = act ? fmaf(s2, (float)(ent >> 10), L2EF * ui) : -INFINITY;
          t2v[q] = t2;
          mx = fmaxf(mx, t2);
        }
        mx = wredMax(mx);
        float sm = 0.f;
#pragma unroll
        for (int q = 0; q < 6; ++q) sm += __builtin_exp2f(t2v[q] - mx);
        sm = wredSum(sm);
        if (lane == 0) astore(v + j, lnu4[cc] - mn - (mx + __builtin_log2f(sm)) * LN2F);
      } else {
        const unsigned short* Rc = Mtq + (long)j * MR;
        for (int k = 0; k < 16; ++k){
          int i = lane + k * 64;
          float t2 = fmaf(s2, (float)Rc[i], L2EF * aload(u + i));
          mx = fmaxf(mx, t2);
        }
        mx = wredMax(mx);
        float sm = 0.f;
        for (int k = 0; k < 16; ++k){
          int i = lane + k * 64;
          float t2 = fmaf(s2, (float)Rc[i], L2EF * aload(u + i));
          sm += __builtin_exp2f(t2 - mx);
        }
        sm = wredSum(sm);
        if (lane == 0) astore(v + j, lnu4[cc] - mn - (mx + __builtin_log2f(sm)) * LN2F);
      }
    }
    gbar(bar, g, ++ep);   // v complete everywhere
  }
}

// fallback (R4 path): used only if cooperative launch fails
__global__ __launch_bounds__(256) void kUPassQ(const unsigned short* __restrict__ Mq,
                                               const float* __restrict__ v,
                                               const float* __restrict__ logmu,
                                               float* __restrict__ u,
                                               const float* __restrict__ prm){
  int b = blockIdx.x, tid = threadIdx.x;
  float mn = prm[2], s = prm[3];
  int r0 = 2 * b;
  const unsigned short* R0 = Mq + (long)r0 * NC;
  const unsigned short* R1 = R0 + NC;
  float t0[32], t1[32];
  float mx0 = -INFINITY, mx1 = -INFINITY;
#pragma unroll
  for (int kb = 0; kb < 4; ++kb){
    int cidx = kb * 2048 + tid * 8;
    uint4 qa = *(const uint4*)(R0 + cidx);
    uint4 qb = *(const uint4*)(R1 + cidx);
    float4 v0 = *(const float4*)(v + cidx);
    float4 v1 = *(const float4*)(v + cidx + 4);
    float a0 = fmaf(s, (float)(qa.x & 0xFFFFu), v0.x);
    float a1 = fmaf(s, (float)(qa.x >> 16),     v0.y);
    float a2 = fmaf(s, (float)(qa.y & 0xFFFFu), v0.z);
    float a3 = fmaf(s, (float)(qa.y >> 16),     v0.w);
    float a4 = fmaf(s, (float)(qa.z & 0xFFFFu), v1.x);
    float a5 = fmaf(s, (float)(qa.z >> 16),     v1.y);
    float a6 = fmaf(s, (float)(qa.w & 0xFFFFu), v1.z);
    float a7 = fmaf(s, (float)(qa.w >> 16),     v1.w);
    float c0 = fmaf(s, (float)(qb.x & 0xFFFFu), v0.x);
    float c1 = fmaf(s, (float)(qb.x >> 16),     v0.y);
    float c2 = fmaf(s, (float)(qb.y & 0xFFFFu), v0.z);
    float c3 = fmaf(s, (float)(qb.y >> 16),     v0.w);
    float c4 = fmaf(s, (float)(qb.z & 0xFFFFu), v1.x);
    float c5 = fmaf(s, (float)(qb.z >> 16),     v1.y);
    float c6 = fmaf(s, (float)(qb.w & 0xFFFFu), v1.z);
    float c7 = fmaf(s, (float)(qb.w >> 16),     v1.w);
    t0[kb*8+0]=a0; t0[kb*8+1]=a1; t0[kb*8+2]=a2; t0[kb*8+3]=a3;
    t0[kb*8+4]=a4; t0[kb*8+5]=a5; t0[kb*8+6]=a6; t0[kb*8+7]=a7;
    t1[kb*8+0]=c0; t1[kb*8+1]=c1; t1[kb*8+2]=c2; t1[kb*8+3]=c3;
    t1[kb*8+4]=c4; t1[kb*8+5]=c5; t1[kb*8+6]=c6; t1[kb*8+7]=c7;
    mx0 = fmaxf(mx0, fmaxf(fmaxf(fmaxf(a0,a1),fmaxf(a2,a3)), fmaxf(fmaxf(a4,a5),fmaxf(a6,a7))));
    mx1 = fmaxf(mx1, fmaxf(fmaxf(fmaxf(c0,c1),fmaxf(c2,c3)), fmaxf(fmaxf(c4,c5),fmaxf(c6,c7))));
  }
  __shared__ float redA0[4], redA1[4], redB0[4], redB1[4];
  int lane = tid & 63, w = tid >> 6;
  float wm0 = wredMax(mx0), wm1 = wredMax(mx1);
  if (lane == 0){ redA0[w] = wm0; redA1[w] = wm1; }
  __syncthreads();
  float bm0 = fmaxf(fmaxf(redA0[0], redA0[1]), fmaxf(redA0[2], redA0[3]));
  float bm1 = fmaxf(fmaxf(redA1[0], redA1[1]), fmaxf(redA1[2], redA1[3]));
  float s0 = 0.f, s1 = 0.f;
#pragma unroll
  for (int q = 0; q < 32; ++q){ s0 += __expf(t0[q] - bm0); s1 += __expf(t1[q] - bm1); }
  s0 = wredSum(s0); s1 = wredSum(s1);
  if (lane == 0){ redB0[w] = s0; redB1[w] = s1; }
  __syncthreads();
  if (tid == 0){
    u[r0]     = logmu[r0]     - mn - (bm0 + __logf(redB0[0] + redB0[1] + redB0[2] + redB0[3]));
    u[r0 + 1] = logmu[r0 + 1] - mn - (bm1 + __logf(redB1[0] + redB1[1] + redB1[2] + redB1[3]));
  }
}

__global__ __launch_bounds__(256) void kVPassQ(const unsigned short* __restrict__ Mtq,
                                               const float* __restrict__ u,
                                               const float* __restrict__ lognu,
                                               float* __restrict__ v,
                                               const float* __restrict__ prm){
  __shared__ float ulds[1024];
  int tid = threadIdx.x;
  float mn = prm[2], s = prm[3];
  *(float4*)(&ulds[tid * 4]) = *(const float4*)(u + tid * 4);
  __syncthreads();
  int w = tid >> 6, lane = tid & 63;
#pragma unroll
  for (int cc = 0; cc < 4; ++cc){
    int j = blockIdx.x * 16 + w * 4 + cc;
    const unsigned short* R = Mtq + (long)j * MR;
    uint4 qa = *(const uint4*)(R + lane * 8);
    uint4 qb = *(const uint4*)(R + 512 + lane * 8);
    float4 ua0 = *(const float4*)(&ulds[lane * 8]);
    float4 ua1 = *(const float4*)(&ulds[lane * 8 + 4]);
    float4 ub0 = *(const float4*)(&ulds[512 + lane * 8]);
    float4 ub1 = *(const float4*)(&ulds[512 + lane * 8 + 4]);
    float tv[16];
    tv[0]  = fmaf(s, (float)(qa.x & 0xFFFFu), ua0.x);
    tv[1]  = fmaf(s, (float)(qa.x >> 16),     ua0.y);
    tv[2]  = fmaf(s, (float)(qa.y & 0xFFFFu), ua0.z);
    tv[3]  = fmaf(s, (float)(qa.y >> 16),     ua0.w);
    tv[4]  = fmaf(s, (float)(qa.z & 0xFFFFu), ua1.x);
    tv[5]  = fmaf(s, (float)(qa.z >> 16),     ua1.y);
    tv[6]  = fmaf(s, (float)(qa.w & 0xFFFFu), ua1.z);
    tv[7]  = fmaf(s, (float)(qa.w >> 16),     ua1.w);
    tv[8]  = fmaf(s, (float)(qb.x & 0xFFFFu), ub0.x);
    tv[9]  = fmaf(s, (float)(qb.x >> 16),     ub0.y);
    tv[10] = fmaf(s, (float)(qb.y & 0xFFFFu), ub0.z);
    tv[11] = fmaf(s, (float)(qb.y >> 16),     ub0.w);
    tv[12] = fmaf(s, (float)(qb.z & 0xFFFFu), ub1.x);
    tv[13] = fmaf(s, (float)(qb.z >> 16),     ub1.y);
    tv[14] = fmaf(s, (float)(qb.w & 0xFFFFu), ub1.z);
    tv[15] = fmaf(s, (float)(qb.w >> 16),     ub1.w);
    float mx = -INFINITY;
#pragma unroll
    for (int q = 0; q < 16; ++q) mx = fmaxf(mx, tv[q]);
    mx = wredMax(mx);
    float sm = 0.f;
#pragma unroll
    for (int q = 0; q < 16; ++q) sm += __expf(tv[q] - mx);
    sm = wredSum(sm);
    if (lane == 0) v[j] = lognu[j] - mn - (mx + __logf(sm));
  }
}

// K5: o = P@T rows, diff = mu*Q - o, acc += sum_i ||diff_i||_2 ; 4 rows per block
__global__ __launch_bounds__(256) void kFinal(const float* __restrict__ x,
                                              const float* __restrict__ att,
                                              const float* __restrict__ M,
                                              const float* __restrict__ u,
                                              const float* __restrict__ v,
                                              float* __restrict__ acc){
  __shared__ float pch[4][256];
  __shared__ float redS[4];
  int tid = threadIdx.x;
  int r0 = blockIdx.x * 4;
  float u4[4];
#pragma unroll
  for (int rr = 0; rr < 4; ++rr) u4[rr] = u[r0 + rr];
  float o[4] = {0.f, 0.f, 0.f, 0.f};
  for (int jc = 0; jc < NC; jc += 256){
    float vv = v[jc + tid];
#pragma unroll
    for (int rr = 0; rr < 4; ++rr)
      pch[rr][tid] = __expf(M[(long)(r0 + rr) * NC + jc + tid] + u4[rr] + vv);
    __syncthreads();
    int k = jc >> 10;
    const float* Tp = x + (1 + k) * IMG_STRIDE + tid * 1024 + (jc & 1023);
    for (int jj = 0; jj < 256; jj += 4){
      float4 tv = *(const float4*)(Tp + jj);
      float tq[4] = {tv.x, tv.y, tv.z, tv.w};
#pragma unroll
      for (int q = 0; q < 4; ++q){
        o[0] += pch[0][jj + q] * tq[q];
        o[1] += pch[1][jj + q] * tq[q];
        o[2] += pch[2][jj + q] * tq[q];
        o[3] += pch[3][jj + q] * tq[q];
      }
    }
    __syncthreads();
  }
  int lane = tid & 63, wid = tid >> 6;
  float dtot = 0.f;
#pragma unroll
  for (int rr = 0; rr < 4; ++rr){
    float mu = att[r0 + rr];
    float qv = x[tid * 1024 + (r0 + rr)];
    float diff = mu * qv - o[rr];
    float wsum = wredSum(diff * diff);
    if (lane == 0) redS[wid] = wsum;
    __syncthreads();
    if (tid == 0) dtot += sqrtf(redS[0] + redS[1] + redS[2] + redS[3]);
    __syncthreads();
  }
  if (tid == 0) atomicAdd(acc, dtot);
}

// K6: apply label/margin, write scalar output
__global__ void kOut(const float* __restrict__ acc, const int* __restrict__ label,
                     float* __restrict__ out){
  if (threadIdx.x == 0 && blockIdx.x == 0){
    float d = *acc;
    out[0] = (*label) ? d : fmaxf(0.7f - d, 0.f);
  }
}

extern "C" void kernel_launch(void* const* d_in, const int* in_sizes, int n_in,
                              void* d_out, int out_size, void* d_ws, size_t ws_size,
                              hipStream_t stream){
  const float* x   = (const float*)d_in[0];
  const float* att = (const float*)d_in[1];
  const int* label = (const int*)d_in[2];
  float* W = (float*)d_ws;
  float* out = (float*)d_out;

  float* M = W;                                                   // 32 MB
  unsigned short* Mq  = (unsigned short*)(W + 8388608);           // 16 MB (fallback path)
  unsigned short* Mtq = (unsigned short*)(W + 8388608 + 4194304); // 16 MB
  float* S     = W + 16777216;
  float* qq    = S;
  float* tt    = qq + 1024;
  float* logmu = tt + 8192;
  float* lognu = logmu + 1024;
  float* u     = lognu + 8192;
  float* v     = u + 1024;
  float* acc   = v + 8192;
  float* prm   = acc + 1;           // [0]=min key, [1]=max key, [2]=mn, [3]=scale
  unsigned* prmI = (unsigned*)prm;
  int*   bar   = (int*)(prm + 4);   // 1024 ints barrier state

  hipLaunchKernelGGL(kPrep, dim3(37), dim3(256), 0, stream, x, att, qq, tt, logmu, lognu, u, v, acc, prmI, bar);
  hipLaunchKernelGGL(kGemmM, dim3(128, 16), dim3(256), 0, stream, x, qq, tt, M, prmI);
  hipLaunchKernelGGL(kQuantTrans, dim3(128, 16), dim3(256), 0, stream, M, Mq, Mtq, prm);

  void* args[] = { (void*)&M, (void*)&Mtq, (void*)&logmu, (void*)&lognu,
                   (void*)&u, (void*)&v, (void*)&prm, (void*)&bar };
  hipError_t rc = hipLaunchCooperativeKernel((const void*)kSink4,
                                             dim3(PBLK), dim3(512), args, 0, stream);
  if (rc != hipSuccess){
    for (int it = 0; it < OT_ITERS; ++it){
      hipLaunchKernelGGL(kUPassQ, dim3(512), dim3(256), 0, stream, Mq, v, logmu, u, prm);
      hipLaunchKernelGGL(kVPassQ, dim3(512), dim3(256), 0, stream, Mtq, u, lognu, v, prm);
    }
  }
  hipLaunchKernelGGL(kFinal, dim3(256), dim3(256), 0, stream, x, att, M, u, v, acc);
  hipLaunchKernelGGL(kOut, dim3(1), dim3(1), 0, stream, acc, label, out);
}